// Round 1
// 227.672 us; speedup vs baseline: 1.0326x; 1.0326x over previous
//
#include <hip/hip_runtime.h>
#include <math.h>

// Problem constants
#define B_     16
#define S_     2048
#define H_     1024
#define NS_    64
#define NC_    4096
#define NROWS  1024   // B_*NS_

#define SCALE_ 30.0f
#define COS_M_ 0.8775825618903728f     // cos(0.5)
#define SIN_M_ 0.479425538604203f      // sin(0.5)
#define TH_    (-0.8775825618903728f)  // cos(pi-0.5)
#define MM_    0.2397127693021015f     // sin(pi-0.5)*0.5
#define LN_EPS_ 1e-7f

// ---------- helpers ----------

__device__ __forceinline__ unsigned short f2bf(float f) {
    union { float f; unsigned int u; } v; v.f = f;
    unsigned int r = v.u + 0x7fffu + ((v.u >> 16) & 1u);   // RNE
    return (unsigned short)(r >> 16);
}

__device__ __forceinline__ float block_sum(float v) {
    __shared__ float sb[4];
    #pragma unroll
    for (int off = 32; off > 0; off >>= 1) v += __shfl_down(v, off, 64);
    if ((threadIdx.x & 63) == 0) sb[threadIdx.x >> 6] = v;
    __syncthreads();
    float r = sb[0] + sb[1] + sb[2] + sb[3];
    __syncthreads();
    return r;
}

__device__ __forceinline__ float block_max(float v) {
    __shared__ float sb[4];
    #pragma unroll
    for (int off = 32; off > 0; off >>= 1) v = fmaxf(v, __shfl_down(v, off, 64));
    if ((threadIdx.x & 63) == 0) sb[threadIdx.x >> 6] = v;
    __syncthreads();
    float r = fmaxf(fmaxf(sb[0], sb[1]), fmaxf(sb[2], sb[3]));
    __syncthreads();
    return r;
}

// async global->LDS, 16 bytes per lane. LDS dest must be waveBase + lane*16.
__device__ __forceinline__ void gload16(const void* g, void* l) {
    __builtin_amdgcn_global_load_lds(
        (const __attribute__((address_space(1))) unsigned int*)g,
        (__attribute__((address_space(3))) unsigned int*)l,
        16, 0, 0);
}

typedef short bf16x8 __attribute__((ext_vector_type(8)));
typedef float f32x4  __attribute__((ext_vector_type(4)));

// ---------- K1: fused  (span mean + LN + l2norm)  and  (wnorm)  ----------
// blocks [0, NROWS)        : span rows  -> embn (bf16)
// blocks [NROWS, NROWS+NC) : arc_weight rows -> Wn (bf16)
__global__ __launch_bounds__(256) void fused_norm_kernel(
    const float* __restrict__ enc,      // [B,S,H]
    const float* __restrict__ gamma,    // [H]
    const float* __restrict__ beta,     // [H]
    const int*   __restrict__ heads,    // [B,NS]
    const int*   __restrict__ tails,    // [B,NS]
    const float* __restrict__ W,        // [NC,H]
    unsigned short* __restrict__ embn,  // [NROWS,H] bf16
    unsigned short* __restrict__ Wn)    // [NC,H] bf16
{
    const int tid = threadIdx.x;

    if (blockIdx.x < NROWS) {
        // ---- span mean + layernorm + l2norm ----
        const int span = blockIdx.x;
        const int b    = span >> 6;
        const int head = heads[span];
        const int tail = tails[span];
        const int cnt  = tail - head;

        const float4* base = (const float4*)(enc + ((size_t)b * S_ + head) * H_) + tid;
        // two independent accumulator chains -> 2 loads in flight per thread
        float a0x=0.f,a0y=0.f,a0z=0.f,a0w=0.f;
        float a1x=0.f,a1y=0.f,a1z=0.f,a1w=0.f;
        int s = 0;
        for (; s + 2 <= cnt; s += 2) {
            float4 x = base[(size_t)s       * (H_ / 4)];
            float4 y = base[(size_t)(s + 1) * (H_ / 4)];
            a0x += x.x; a0y += x.y; a0z += x.z; a0w += x.w;
            a1x += y.x; a1y += y.y; a1z += y.z; a1w += y.w;
        }
        if (s < cnt) {
            float4 x = base[(size_t)s * (H_ / 4)];
            a0x += x.x; a0y += x.y; a0z += x.z; a0w += x.w;
        }
        const float inv = 1.0f / (float)cnt;
        float v0 = (a0x + a1x) * inv, v1 = (a0y + a1y) * inv;
        float v2 = (a0z + a1z) * inv, v3 = (a0w + a1w) * inv;

        float mu = block_sum(v0 + v1 + v2 + v3) * (1.0f / H_);
        float d0 = v0 - mu, d1 = v1 - mu, d2 = v2 - mu, d3 = v3 - mu;
        float var = block_sum(d0*d0 + d1*d1 + d2*d2 + d3*d3) * (1.0f / H_);
        float rstd = rsqrtf(var + LN_EPS_);

        const int h = tid * 4;
        float y0 = d0 * rstd * gamma[h+0] + beta[h+0];
        float y1 = d1 * rstd * gamma[h+1] + beta[h+1];
        float y2 = d2 * rstd * gamma[h+2] + beta[h+2];
        float y3 = d3 * rstd * gamma[h+3] + beta[h+3];

        float ss = block_sum(y0*y0 + y1*y1 + y2*y2 + y3*y3);
        float invn = 1.0f / fmaxf(sqrtf(ss), 1e-12f);

        ushort4 o;
        o.x = f2bf(y0 * invn); o.y = f2bf(y1 * invn);
        o.z = f2bf(y2 * invn); o.w = f2bf(y3 * invn);
        *(ushort4*)(embn + (size_t)span * H_ + h) = o;
    } else {
        // ---- l2-normalize arc_weight row ----
        const int row = blockIdx.x - NROWS;
        float4 x = ((const float4*)(W + (size_t)row * H_))[tid];
        float ss = block_sum(x.x*x.x + x.y*x.y + x.z*x.z + x.w*x.w);
        float invn = 1.0f / fmaxf(sqrtf(ss), 1e-12f);
        ushort4 o;
        o.x = f2bf(x.x * invn); o.y = f2bf(x.y * invn);
        o.z = f2bf(x.z * invn); o.w = f2bf(x.w * invn);
        *(ushort4*)(Wn + (size_t)row * H_ + tid * 4) = o;
    }
}

// ---------- K2: cosine = embn @ Wn^T  (NT bf16 MFMA GEMM) ----------
// M=1024, N=4096, K=1024. 128x128 tile, BK=64, double-buffered LDS,
// 2-phase pipeline (stage next || compute cur, one vmcnt(0)+barrier per tile),
// XOR-swizzled LDS (pre-swizzled global source, swizzled ds_read),
// bijective XCD swizzle (256 blocks, 256%8==0).
__global__ __launch_bounds__(256, 1) void gemm_kernel(
    const unsigned short* __restrict__ A,   // [1024,1024] bf16 row-major
    const unsigned short* __restrict__ Bw,  // [4096,1024] bf16 row-major
    float* __restrict__ C)                  // [1024,4096] fp32
{
    __shared__ short As[2][128 * 64];   // 16KB per buffer
    __shared__ short Bs[2][128 * 64];   // total 64KB

    // XCD-aware bijective swizzle: XCD k works tiles n in [4k,4k+4) x all m
    // -> per-XCD L2 set = A(2MB) + 4 B-panels(1MB) = 3MB < 4MB.
    const int bid = blockIdx.y * 8 + blockIdx.x;   // dispatch-order flat id
    const int swz = (bid & 7) * 32 + (bid >> 3);
    const int m0  = (swz & 7) * 128;
    const int n0  = (swz >> 3) * 128;

    const int tid  = threadIdx.x;
    const int lane = tid & 63;
    const int w    = tid >> 6;
    const int wm   = (w & 1) * 64;
    const int wn   = (w >> 1) * 64;
    const int lrow = lane & 15;
    const int q    = lane >> 4;
    const int xr   = lrow & 7;       // read-side XOR key (== row&7 since wm,i*16 are mult of 8)

    // staging decomposition: thread t, sub-load i: linear slot = i*256+t
    // row = slot>>3 (0..127), c16 = slot&7 (16B-column).  LDS dest is linear
    // (waveBase + lane*16 by construction); the global SOURCE is pre-swizzled:
    // LDS slot (row, c16) holds global 16B-column (c16 ^ (row&7)).
    const int srow = tid >> 3;       // 0..31, +i*32
    const int sc16 = tid & 7;

    f32x4 acc[4][4];
    #pragma unroll
    for (int i = 0; i < 4; ++i)
        #pragma unroll
        for (int j = 0; j < 4; ++j)
            acc[i][j] = (f32x4){0.f, 0.f, 0.f, 0.f};

    auto stage = [&](int bsel, int k0) {
        #pragma unroll
        for (int i = 0; i < 4; ++i) {
            const int row = i * 32 + srow;
            const int s16 = sc16 ^ (row & 7);
            gload16(A  + (size_t)(m0 + row) * 1024 + k0 + s16 * 8,
                    &As[bsel][row * 64 + sc16 * 8]);
            gload16(Bw + (size_t)(n0 + row) * 1024 + k0 + s16 * 8,
                    &Bs[bsel][row * 64 + sc16 * 8]);
        }
    };

    auto compute = [&](int bsel) {
        #pragma unroll
        for (int kk = 0; kk < 2; ++kk) {
            const int c16 = ((kk << 2) | q) ^ xr;   // swizzled 16B column
            bf16x8 af[4], bfr[4];
            #pragma unroll
            for (int i = 0; i < 4; ++i)
                af[i] = *(const bf16x8*)(&As[bsel][(wm + i * 16 + lrow) * 64 + c16 * 8]);
            #pragma unroll
            for (int j = 0; j < 4; ++j)
                bfr[j] = *(const bf16x8*)(&Bs[bsel][(wn + j * 16 + lrow) * 64 + c16 * 8]);
            #pragma unroll
            for (int i = 0; i < 4; ++i)
                #pragma unroll
                for (int j = 0; j < 4; ++j)
                    acc[i][j] = __builtin_amdgcn_mfma_f32_16x16x32_bf16(af[i], bfr[j], acc[i][j], 0, 0, 0);
        }
    };

    // prologue
    stage(0, 0);
    asm volatile("s_waitcnt vmcnt(0)" ::: "memory");
    __builtin_amdgcn_s_barrier();

    int cur = 0;
    for (int t = 0; t < 15; ++t) {
        stage(cur ^ 1, (t + 1) * 64);    // prefetch next tile (in flight across compute)
        compute(cur);                    // ds_read deps drained by compiler lgkmcnt before MFMA
        asm volatile("s_waitcnt vmcnt(0)" ::: "memory");
        __builtin_amdgcn_s_barrier();
        cur ^= 1;
    }
    compute(cur);                        // last tile (staged at t=14)

    // C/D layout: col = lane&15, row = (lane>>4)*4 + reg  [m89/m91]
    #pragma unroll
    for (int i = 0; i < 4; ++i) {
        const int rbase = m0 + wm + i * 16 + q * 4;
        #pragma unroll
        for (int j = 0; j < 4; ++j) {
            const int col = n0 + wn + j * 16 + lrow;
            #pragma unroll
            for (int r2 = 0; r2 < 4; ++r2)
                C[(size_t)(rbase + r2) * NC_ + col] = acc[i][j][r2];
        }
    }
}

// ---------- K3: ArcFace label fix + log-softmax CE per row ----------
__global__ __launch_bounds__(256) void ce_kernel(
    const float* __restrict__ cosine,   // [NROWS,NC]
    const int*   __restrict__ labels,   // [NROWS]
    float* __restrict__ nll)            // [NROWS]
{
    __shared__ float s_lab;
    const int row = blockIdx.x;
    const int lab = labels[row];
    const int tid = threadIdx.x;
    const float4* c4 = (const float4*)(cosine + (size_t)row * NC_);

    float vals[16];
    float m = -1e30f;
    #pragma unroll
    for (int t = 0; t < 4; ++t) {
        float4 x = c4[tid + t * 256];
        const int cbase = (tid + t * 256) * 4;
        float xs[4] = {x.x, x.y, x.z, x.w};
        #pragma unroll
        for (int k = 0; k < 4; ++k) {
            float c = xs[k];
            float logit = c;
            if (cbase + k == lab) {
                float sine = sqrtf(fmaxf(1.0f - c * c, 0.0f));
                float phi  = c * COS_M_ - sine * SIN_M_;
                logit = (c > TH_) ? phi : (c - MM_);
            }
            logit *= SCALE_;
            vals[t * 4 + k] = logit;
            if (cbase + k == lab) s_lab = logit;
            m = fmaxf(m, logit);
        }
    }
    float gm = block_max(m);          // contains __syncthreads -> s_lab visible
    float e = 0.f;
    #pragma unroll
    for (int t = 0; t < 16; ++t) e += expf(vals[t] - gm);
    float se = block_sum(e);
    if (tid == 0) nll[row] = logf(se) + gm - s_lab;
}

// ---------- K4: mean over rows ----------
__global__ __launch_bounds__(256) void mean_kernel(
    const float* __restrict__ nll, float* __restrict__ out)
{
    const int tid = threadIdx.x;
    float s = 0.f;
    #pragma unroll
    for (int t = 0; t < 4; ++t) s += nll[tid + t * 256];
    float tot = block_sum(s);
    if (tid == 0) out[0] = tot * (1.0f / NROWS);
}

// ---------- launch ----------
extern "C" void kernel_launch(void* const* d_in, const int* in_sizes, int n_in,
                              void* d_out, int out_size, void* d_ws, size_t ws_size,
                              hipStream_t stream) {
    const float* enc    = (const float*)d_in[0];
    const float* gamma  = (const float*)d_in[1];
    const float* beta   = (const float*)d_in[2];
    const float* W      = (const float*)d_in[3];
    const int*   heads  = (const int*)d_in[4];
    const int*   tails  = (const int*)d_in[5];
    const int*   labels = (const int*)d_in[6];
    float* out = (float*)d_out;

    char* ws = (char*)d_ws;
    unsigned short* embn   = (unsigned short*)(ws);                       // 2 MB
    unsigned short* Wn     = (unsigned short*)(ws + (2u  << 20));         // 8 MB
    float*          cosine = (float*)        (ws + (10u << 20));          // 16 MB
    float*          nllbuf = (float*)        (ws + (26u << 20));          // 4 KB

    fused_norm_kernel<<<NROWS + NC_, 256, 0, stream>>>(enc, gamma, beta, heads, tails, W, embn, Wn);
    dim3 g3(8, 32);
    gemm_kernel <<<g3,  256, 0, stream>>>(embn, Wn, cosine);
    ce_kernel   <<<NROWS, 256, 0, stream>>>(cosine, labels, nllbuf);
    mean_kernel <<<1,     256, 0, stream>>>(nllbuf, out);
}